// Round 11
// baseline (639.012 us; speedup 1.0000x reference)
//
#include <hip/hip_runtime.h>
#include <stdint.h>

typedef unsigned short u16;
typedef __bf16 bf16x2 __attribute__((ext_vector_type(2)));
typedef __bf16 bf16x8 __attribute__((ext_vector_type(8)));
typedef float f32x4 __attribute__((ext_vector_type(4)));
typedef float f32x16 __attribute__((ext_vector_type(16)));
typedef unsigned int u32x4 __attribute__((ext_vector_type(4)));
typedef u16 u16x8 __attribute__((ext_vector_type(8)));
typedef u16 u16x4 __attribute__((ext_vector_type(4)));

#define MFMA16(a, b, c) __builtin_amdgcn_mfma_f32_16x16x32_bf16((a), (b), (c), 0, 0, 0)
#define MFMA32(a, b, c) __builtin_amdgcn_mfma_f32_32x32x16_bf16((a), (b), (c), 0, 0, 0)

// 0.125 (1/sqrt(64)) * log2(e): folded into Q so softmax uses exp2 directly
#define QSCALE 0.18033688011112042f

#if defined(__has_builtin)
#if __has_builtin(__builtin_amdgcn_exp2f)
#define EXP2(x) __builtin_amdgcn_exp2f(x)
#endif
#endif
#ifndef EXP2
#define EXP2(x) __expf((x) * 0.6931471805599453f)
#endif

__device__ __forceinline__ u16 f2bf(float f) {
  return __builtin_bit_cast(u16, (__bf16)f);  // RNE
}

__device__ __forceinline__ unsigned cvtpk(float lo, float hi) {
  bf16x2 t;
  t[0] = (__bf16)lo;
  t[1] = (__bf16)hi;
  return __builtin_bit_cast(unsigned, t);  // v_cvt_pk_bf16_f32
}

__device__ __forceinline__ bf16x8 load_frag(const u16* lds_base, int byteoff) {
  u32x4 v = *(const u32x4*)((const char*)lds_base + byteoff);
  return __builtin_bit_cast(bf16x8, v);
}

#define GLOAD_LDS16(gp, lp)                                                        \
  __builtin_amdgcn_global_load_lds((const __attribute__((address_space(1))) void*)(gp), \
                                   (__attribute__((address_space(3))) void*)(lp), 16, 0, 0)

// Stage ROWS x 64-bf16 tile (128B rows) from global (row stride ld elems) into
// swizzled LDS. Physical 16B-slot `seg` holds logical slot `seg ^ (row&7)`.
template <int ROWS>
__device__ __forceinline__ void stage_tile(const u16* __restrict__ src, int ld, u16* lds,
                                           int tid) {
  constexpr int SLOTS = ROWS * 8;
#pragma unroll
  for (int it = 0; it < SLOTS / 256; ++it) {
    const int s = it * 256 + tid;
    const int row = s >> 3;
    const int seg = (s & 7) ^ (row & 7);
    const u16* g = src + row * ld + seg * 8;
    u16* l = lds + (it * 256 + (tid & ~63)) * 8;  // wave-uniform base; HW adds lane*16
    GLOAD_LDS16(g, l);
  }
}

// ---------------- converts ----------------

__global__ __launch_bounds__(256) void cvt_x(const float* __restrict__ in,
                                             u16* __restrict__ out) {
  const int i = (int)blockIdx.x * 256 + (int)threadIdx.x;
  const float4 a = ((const float4*)in)[2 * i];
  const float4 b = ((const float4*)in)[2 * i + 1];
  u16x8 o;
  o[0] = f2bf(a.x); o[1] = f2bf(a.y); o[2] = f2bf(a.z); o[3] = f2bf(a.w);
  o[4] = f2bf(b.x); o[5] = f2bf(b.y); o[6] = f2bf(b.z); o[7] = f2bf(b.w);
  ((u16x8*)out)[i] = o;
}

// W [1024][1024] fp32 row-major -> Wt [1024][1024] bf16, Wt[n][k] = W[k][n]
// blockIdx.z selects which of the 4 weight matrices (merged launch)
__global__ __launch_bounds__(256) void cvt_w_t4(const float* __restrict__ W0,
                                                const float* __restrict__ W1,
                                                const float* __restrict__ W2,
                                                const float* __restrict__ W3,
                                                u16* __restrict__ T0, u16* __restrict__ T1,
                                                u16* __restrict__ T2, u16* __restrict__ T3) {
  const int z = (int)blockIdx.z;
  const float* W = z == 0 ? W0 : (z == 1 ? W1 : (z == 2 ? W2 : W3));
  u16* Wt = z == 0 ? T0 : (z == 1 ? T1 : (z == 2 ? T2 : T3));

  __shared__ u16 t[64][65];
  const int tid = (int)threadIdx.x;
  const int r = tid >> 2;
  const int cs = (tid & 3) * 16;
  const int tr = (int)blockIdx.y * 64;
  const int tc = (int)blockIdx.x * 64;
#pragma unroll
  for (int i = 0; i < 16; i += 4) {
    const float4 v = *(const float4*)&W[(size_t)(tr + r) * 1024 + tc + cs + i];
    t[r][cs + i + 0] = f2bf(v.x);
    t[r][cs + i + 1] = f2bf(v.y);
    t[r][cs + i + 2] = f2bf(v.z);
    t[r][cs + i + 3] = f2bf(v.w);
  }
  __syncthreads();
  u16 tmp[16];
#pragma unroll
  for (int i = 0; i < 16; ++i) tmp[i] = t[cs + i][r];
  u16x8 o0, o1;
#pragma unroll
  for (int i = 0; i < 8; ++i) { o0[i] = tmp[i]; o1[i] = tmp[8 + i]; }
  *(u16x8*)&Wt[(size_t)(tc + r) * 1024 + tr + cs] = o0;
  *(u16x8*)&Wt[(size_t)(tc + r) * 1024 + tr + cs + 8] = o1;
}

// ---------------- GEMM epilogue addressing helpers ----------------

__device__ __forceinline__ size_t vfrag_addr(int row, int col) {
  const int b = row >> 11, s = row & 2047;
  const int h = col >> 6, d = col & 63;
  return ((size_t)((b * 16 + h) * 32 + (s >> 6))) * 4096 + (size_t)(d >> 5) * 2048 +
         (size_t)((s & 63) >> 4) * 512 + (size_t)((d & 31) | (((s >> 3) & 1) << 5)) * 8 +
         (s & 7);
}

__device__ __forceinline__ size_t kfrag_addr(int row, int col) {
  const int b = row >> 11, s = row & 2047;
  const int h = col >> 6, d = col & 63;
  return ((size_t)((b * 16 + h) * 64 + (s >> 5))) * 2048 + (size_t)(d >> 4) * 512 +
         (size_t)((s & 31) | (((d >> 3) & 1) << 5)) * 8 + (d & 7);
}

// ---------------- GEMM K-loop core (128x128 tile, BK=64) ----------------
// Double-buffered LDS pipeline: stage tile t+1 BEFORE computing tile t;
// ONE barrier per K-step. LDS: buf b at lds + b*16384; A at +0, B at +8192.

__device__ __forceinline__ void compute_tile(const u16* __restrict__ buf, int wm, int wn,
                                             int lr, int lg, f32x4 (&acc)[4][4]) {
#pragma unroll
  for (int ks = 0; ks < 2; ++ks) {
    bf16x8 af[4], bf[4];
#pragma unroll
    for (int i = 0; i < 4; ++i) {
      const int ar = wm * 64 + i * 16 + lr;
      af[i] = load_frag(buf, ar * 128 + ((ks * 64 + lg * 16) ^ ((ar & 7) << 4)));
      const int br = wn * 64 + i * 16 + lr;
      bf[i] = load_frag(buf + 8192, br * 128 + ((ks * 64 + lg * 16) ^ ((br & 7) << 4)));
    }
#pragma unroll
    for (int mf = 0; mf < 4; ++mf)
#pragma unroll
      for (int nf = 0; nf < 4; ++nf) acc[mf][nf] = MFMA16(af[mf], bf[nf], acc[mf][nf]);
  }
}

__device__ __forceinline__ void gemm_core(const u16* __restrict__ Abase,
                                          const u16* __restrict__ Bbase, u16* lds, int tid,
                                          int wm, int wn, int lr, int lg,
                                          f32x4 (&acc)[4][4]) {
  constexpr int K = 1024;
  stage_tile<128>(Abase, K, lds, tid);
  stage_tile<128>(Bbase, K, lds + 8192, tid);
  __syncthreads();
  int cur = 0;
#pragma unroll 1
  for (int k0 = 64; k0 < K; k0 += 64) {
    u16* nbuf = lds + (cur ^ 1) * 16384;
    stage_tile<128>(Abase + k0, K, nbuf, tid);       // issue next-tile loads first
    stage_tile<128>(Bbase + k0, K, nbuf + 8192, tid);
    compute_tile(lds + cur * 16384, wm, wn, lr, lg, acc);  // MFMA hides load latency
    __syncthreads();
    cur ^= 1;
  }
  compute_tile(lds + cur * 16384, wm, wn, lr, lg, acc);
}

// ---------------- merged QKV GEMM: grid (24, 64) ----------------
// blockIdx.x>>3 selects matrix: 0=Q (row-major, scaled), 1=K (frag), 2=V (frag)

__global__ __launch_bounds__(256) void gemm_qkv(const u16* __restrict__ A,
                                                const u16* __restrict__ Bq,
                                                const u16* __restrict__ Bk,
                                                const u16* __restrict__ Bv,
                                                const float* __restrict__ bq,
                                                const float* __restrict__ bk,
                                                const float* __restrict__ bv,
                                                u16* __restrict__ Qo, u16* __restrict__ Ko,
                                                u16* __restrict__ Vo) {
  __shared__ __align__(16) u16 lds[32768];  // 64 KB: 2 dbuf x (A+B) x 128x64
  const int tid = (int)threadIdx.x;
  const int w = tid >> 6, lane = tid & 63;
  const int wm = w >> 1, wn = w & 1;
  const int lr = lane & 15, lg = lane >> 4;
  const int g = (int)blockIdx.x;
  const int m_idx = g >> 3, nt = g & 7;
  const int mt = (int)blockIdx.y;

  const u16* Bt = m_idx == 0 ? Bq : (m_idx == 1 ? Bk : Bv);
  const float* bias = m_idx == 0 ? bq : (m_idx == 1 ? bk : bv);

  f32x4 acc[4][4] = {};
  gemm_core(A + (size_t)mt * 128 * 1024, Bt + (size_t)nt * 128 * 1024, lds, tid, wm, wn, lr,
            lg, acc);

#pragma unroll
  for (int mf = 0; mf < 4; ++mf) {
#pragma unroll
    for (int nf = 0; nf < 4; ++nf) {
      const int col = nt * 128 + wn * 64 + nf * 16 + lr;
      const float bv2 = bias[col];
#pragma unroll
      for (int r = 0; r < 4; ++r) {
        const int row = mt * 128 + wm * 64 + mf * 16 + lg * 4 + r;
        const float v = acc[mf][nf][r] + bv2;
        if (m_idx == 0) {
          Qo[(size_t)row * 1024 + col] = f2bf(v * QSCALE);
        } else if (m_idx == 1) {
          Ko[kfrag_addr(row, col)] = f2bf(v);
        } else {
          Vo[vfrag_addr(row, col)] = f2bf(v);
        }
      }
    }
  }
}

// ---------------- final GEMM: out = Ab @ Wo^T + bo (fp32 out) ----------------

__global__ __launch_bounds__(256) void gemm_out(const u16* __restrict__ A,
                                                const u16* __restrict__ Bt,
                                                const float* __restrict__ bias,
                                                float* __restrict__ Cout) {
  __shared__ __align__(16) u16 lds[32768];
  const int tid = (int)threadIdx.x;
  const int w = tid >> 6, lane = tid & 63;
  const int wm = w >> 1, wn = w & 1;
  const int lr = lane & 15, lg = lane >> 4;
  const int mt = (int)blockIdx.y, nt = (int)blockIdx.x;

  f32x4 acc[4][4] = {};
  gemm_core(A + (size_t)mt * 128 * 1024, Bt + (size_t)nt * 128 * 1024, lds, tid, wm, wn, lr,
            lg, acc);

#pragma unroll
  for (int mf = 0; mf < 4; ++mf) {
#pragma unroll
    for (int nf = 0; nf < 4; ++nf) {
      const int col = nt * 128 + wn * 64 + nf * 16 + lr;
      const float bv = bias[col];
#pragma unroll
      for (int r = 0; r < 4; ++r) {
        const int row = mt * 128 + wm * 64 + mf * 16 + lg * 4 + r;
        Cout[(size_t)row * 1024 + col] = acc[mf][nf][r] + bv;
      }
    }
  }
}

// ---------------- flash attention (causal), swapped-operand, LDS-free ----------------
// 4-wave blocks; all 4 waves have IDENTICAL work (33 K/V tiles):
// wave w of block (xcd, rr, slot) does stripe qs0=slot*4+w of bh=(xcd<<3)|rr,
// then stripe 63-qs0 of bh^1 (same XCD L2 set). K ping-pong prefetch restored.
// Softmax in log2 units, in-register; split reduction chains.

__device__ __forceinline__ void loadK(bf16x8 (&kf)[2][4], const u16* __restrict__ p) {
#pragma unroll
  for (int sb = 0; sb < 2; ++sb)
#pragma unroll
    for (int dk = 0; dk < 4; ++dk)
      kf[sb][dk] = *(const bf16x8*)(p + sb * 2048 + dk * 512);
}

__device__ __forceinline__ void attn_tile(const bf16x8 (&kf)[2][4],
                                          const u16* __restrict__ vp_tile,
                                          const bf16x8 (&qf)[4], const int hi,
                                          const bool masked, const int tmask, f32x16& o0,
                                          f32x16& o1, float& m_run, float& l_run) {
  bf16x8 vf[2][4];
#pragma unroll
  for (int db = 0; db < 2; ++db)
#pragma unroll
    for (int ks = 0; ks < 4; ++ks)
      vf[db][ks] = *(const bf16x8*)(vp_tile + db * 2048 + ks * 512);

  // S^T: p0 = keys [0,32), p1 = keys [32,64); lane&31 = q, reg r -> k_local
  f32x16 p0 = {}, p1 = {};
#pragma unroll
  for (int dk = 0; dk < 4; ++dk) {
    p0 = MFMA32(kf[0][dk], qf[dk], p0);
    p1 = MFMA32(kf[1][dk], qf[dk], p1);
  }

  if (masked) {  // wave-uniform branch: only the last tile pays
#pragma unroll
    for (int r = 0; r < 16; ++r) {
      const int kl = (r & 3) + 8 * (r >> 2) + 4 * hi;
      if (kl > tmask) p0[r] = -1.0e30f;
      if (kl + 32 > tmask) p1[r] = -1.0e30f;
    }
  }

  // two parallel max chains (v_max3), then combine
  float mx0 = -3.0e38f, mx1 = -3.0e38f;
#pragma unroll
  for (int r = 0; r < 16; r += 2) {
    mx0 = fmaxf(mx0, fmaxf(p0[r], p0[r + 1]));
    mx1 = fmaxf(mx1, fmaxf(p1[r], p1[r + 1]));
  }
  float mx = fmaxf(mx0, mx1);
  mx = fmaxf(mx, __shfl_xor(mx, 32));

  // defer-max (T13): THR = 8 nats = 11.5416 log2-units
  if (__any(mx > m_run + 11.5416f)) {
    const float mnew = fmaxf(m_run, mx);
    const float alpha = EXP2(m_run - mnew);
    m_run = mnew;
    l_run *= alpha;
#pragma unroll
    for (int r = 0; r < 16; ++r) { o0[r] *= alpha; o1[r] *= alpha; }
  }

  // four parallel sum chains
  float rs0 = 0.f, rs1 = 0.f, rs2 = 0.f, rs3 = 0.f;
#pragma unroll
  for (int r = 0; r < 16; r += 2) {
    p0[r] = EXP2(p0[r] - m_run);
    p0[r + 1] = EXP2(p0[r + 1] - m_run);
    p1[r] = EXP2(p1[r] - m_run);
    p1[r + 1] = EXP2(p1[r + 1] - m_run);
    rs0 += p0[r];
    rs1 += p0[r + 1];
    rs2 += p1[r];
    rs3 += p1[r + 1];
  }
  float rs = (rs0 + rs1) + (rs2 + rs3);
  rs += __shfl_xor(rs, 32);
  l_run += rs;

  // P^T B-fragments: 16 cvt_pk words + 8 permlane32_swap
  unsigned c[16];
#pragma unroll
  for (int j = 0; j < 8; ++j) {
    c[j] = cvtpk(p0[2 * j], p0[2 * j + 1]);
    c[8 + j] = cvtpk(p1[2 * j], p1[2 * j + 1]);
  }
  bf16x8 pf[4];
#pragma unroll
  for (int ks = 0; ks < 4; ++ks) {
    const int base = (ks >> 1) * 8 + (ks & 1) * 4;
    auto s0 = __builtin_amdgcn_permlane32_swap(c[base + 0], c[base + 2], false, false);
    auto s1 = __builtin_amdgcn_permlane32_swap(c[base + 1], c[base + 3], false, false);
    u32x4 wv;
    wv[0] = s0[0];
    wv[1] = s1[0];
    wv[2] = s0[1];
    wv[3] = s1[1];
    pf[ks] = __builtin_bit_cast(bf16x8, wv);
  }

  // O^T += V^T . P^T
#pragma unroll
  for (int ks = 0; ks < 4; ++ks) {
    o0 = MFMA32(vf[0][ks], pf[ks], o0);
    o1 = MFMA32(vf[1][ks], pf[ks], o1);
  }
}

__global__ __launch_bounds__(256, 4) void attn_fwd(const u16* __restrict__ Qb,
                                                   const u16* __restrict__ Kf,
                                                   const u16* __restrict__ Vf,
                                                   u16* __restrict__ Ab) {
  const int tid = (int)threadIdx.x;
  const int w = tid >> 6, lane = tid & 63;
  const int ln = lane & 31, hi = lane >> 5;

  // grid 1024 = (xcd 8) x (bh-in-xcd 8) x (slot 16); 4 identical waves/block
  const int id = (int)blockIdx.x;
  const int xcd = id & 7;
  const int rr = (id >> 3) & 7;
  const int qs0 = (id >> 6) * 4 + w;  // 0..63

#pragma unroll 1
  for (int pass = 0; pass < 2; ++pass) {
    const int bh = (xcd << 3) | (pass ? (rr ^ 1) : rr);
    const int qs = pass ? 63 - qs0 : qs0;
    const int b = bh >> 4, h = bh & 15;
    const int wq = qs * 32;
    const int qrow = wq + ln;

    const u16* qp = Qb + (size_t)(b * 2048 + qrow) * 1024 + h * 64 + hi * 8;
    bf16x8 qf[4];
#pragma unroll
    for (int dk = 0; dk < 4; ++dk) qf[dk] = *(const bf16x8*)(qp + dk * 16);

    const u16* kp = Kf + (size_t)bh * 131072 + lane * 8;
    const u16* vp = Vf + (size_t)bh * 131072 + lane * 8;

    f32x16 o0 = {}, o1 = {};
    float m_run = -3.0e38f, l_run = 0.0f;

    const int nt = (qs >> 1) + 1;  // tiles incl. final masked one
    bf16x8 kA[2][4], kB[2][4];
    loadK(kA, kp);
    int i = 0;
    while (i + 2 <= nt) {
      loadK(kB, kp + (size_t)(i + 1) * 4096);
      attn_tile(kA, vp + (size_t)i * 4096, qf, hi, false, 0, o0, o1, m_run, l_run);
      const int nx = (i + 2 < nt) ? i + 2 : i + 1;
      loadK(kA, kp + (size_t)nx * 4096);
      attn_tile(kB, vp + (size_t)(i + 1) * 4096, qf, hi, i + 2 == nt, qrow - (i + 1) * 64,
                o0, o1, m_run, l_run);
      i += 2;
    }
    if (i < nt)
      attn_tile(kA, vp + (size_t)i * 4096, qf, hi, true, qrow - i * 64, o0, o1, m_run,
                l_run);

    const float inv = 1.0f / l_run;
    u16* op = Ab + (size_t)(b * 2048 + qrow) * 1024 + h * 64;
#pragma unroll
    for (int rr2 = 0; rr2 < 4; ++rr2) {
      u16x4 s0v, s1v;
#pragma unroll
      for (int cc = 0; cc < 4; ++cc) {
        s0v[cc] = f2bf(o0[rr2 * 4 + cc] * inv);
        s1v[cc] = f2bf(o1[rr2 * 4 + cc] * inv);
      }
      *(u16x4*)(op + rr2 * 8 + hi * 4) = s0v;       // d = 8*rr2 + 4*hi + 0..3
      *(u16x4*)(op + 32 + rr2 * 8 + hi * 4) = s1v;  // d = 32 + ...
    }
  }
}

// ---------------- launch ----------------

extern "C" void kernel_launch(void* const* d_in, const int* in_sizes, int n_in, void* d_out,
                              int out_size, void* d_ws, size_t ws_size, hipStream_t stream) {
  const float* X = (const float*)d_in[0];
  const float* Wq = (const float*)d_in[1];
  const float* bq = (const float*)d_in[2];
  const float* Wk = (const float*)d_in[3];
  const float* bk = (const float*)d_in[4];
  const float* Wv = (const float*)d_in[5];
  const float* bv = (const float*)d_in[6];
  const float* Wo = (const float*)d_in[7];
  const float* bo = (const float*)d_in[8];
  float* out = (float*)d_out;

  u16* ws = (u16*)d_ws;
  u16* Xb = ws;                    // 8192x1024 bf16 X
  u16* Wqt = Xb + 8388608;         // 1024x1024 bf16 Wq^T
  u16* Wkt = Wqt + 1048576;
  u16* Wvt = Wkt + 1048576;
  u16* Wot = Wvt + 1048576;
  u16* Qb = Wot + 1048576;         // 8192x1024 bf16 Q (pre-scaled by QSCALE)
  u16* Kf = Qb + 8388608;          // K fragment layout [bh][kb32][dk][lane][8]
  u16* Vf = Kf + 8388608;          // V fragment layout [bh][tile64][db][ks][lane][8]
  u16* Ab = Vf + 8388608;          // 8192x1024 bf16 attn out

  cvt_x<<<4096, 256, 0, stream>>>(X, Xb);
  dim3 wtg(16, 16, 4);
  cvt_w_t4<<<wtg, 256, 0, stream>>>(Wq, Wk, Wv, Wo, Wqt, Wkt, Wvt, Wot);

  dim3 qkvg(24, 64);
  gemm_qkv<<<qkvg, 256, 0, stream>>>(Xb, Wqt, Wkt, Wvt, bq, bk, bv, Qb, Kf, Vf);

  attn_fwd<<<1024, 256, 0, stream>>>(Qb, Kf, Vf, Ab);

  dim3 gg(8, 64);
  gemm_out<<<gg, 256, 0, stream>>>(Ab, Wot, bo, out);
}

// Round 12
// 230.364 us; speedup vs baseline: 2.7739x; 2.7739x over previous
//
#include <hip/hip_runtime.h>
#include <stdint.h>

typedef unsigned short u16;
typedef __bf16 bf16x2 __attribute__((ext_vector_type(2)));
typedef __bf16 bf16x8 __attribute__((ext_vector_type(8)));
typedef float f32x4 __attribute__((ext_vector_type(4)));
typedef float f32x16 __attribute__((ext_vector_type(16)));
typedef unsigned int u32x4 __attribute__((ext_vector_type(4)));
typedef u16 u16x8 __attribute__((ext_vector_type(8)));
typedef u16 u16x4 __attribute__((ext_vector_type(4)));

#define MFMA16(a, b, c) __builtin_amdgcn_mfma_f32_16x16x32_bf16((a), (b), (c), 0, 0, 0)
#define MFMA32(a, b, c) __builtin_amdgcn_mfma_f32_32x32x16_bf16((a), (b), (c), 0, 0, 0)

// 0.125 (1/sqrt(64)) * log2(e): folded into Q so softmax uses exp2 directly
#define QSCALE 0.18033688011112042f

#if defined(__has_builtin)
#if __has_builtin(__builtin_amdgcn_exp2f)
#define EXP2(x) __builtin_amdgcn_exp2f(x)
#endif
#endif
#ifndef EXP2
#define EXP2(x) __expf((x) * 0.6931471805599453f)
#endif

__device__ __forceinline__ u16 f2bf(float f) {
  return __builtin_bit_cast(u16, (__bf16)f);  // RNE
}

__device__ __forceinline__ unsigned cvtpk(float lo, float hi) {
  bf16x2 t;
  t[0] = (__bf16)lo;
  t[1] = (__bf16)hi;
  return __builtin_bit_cast(unsigned, t);  // v_cvt_pk_bf16_f32
}

__device__ __forceinline__ bf16x8 load_frag(const u16* lds_base, int byteoff) {
  u32x4 v = *(const u32x4*)((const char*)lds_base + byteoff);
  return __builtin_bit_cast(bf16x8, v);
}

#define GLOAD_LDS16(gp, lp)                                                        \
  __builtin_amdgcn_global_load_lds((const __attribute__((address_space(1))) void*)(gp), \
                                   (__attribute__((address_space(3))) void*)(lp), 16, 0, 0)

// Stage ROWS x 64-bf16 tile (128B rows) from global (row stride ld elems) into
// swizzled LDS. Physical 16B-slot `seg` holds logical slot `seg ^ (row&7)`.
template <int ROWS>
__device__ __forceinline__ void stage_tile(const u16* __restrict__ src, int ld, u16* lds,
                                           int tid) {
  constexpr int SLOTS = ROWS * 8;
#pragma unroll
  for (int it = 0; it < SLOTS / 256; ++it) {
    const int s = it * 256 + tid;
    const int row = s >> 3;
    const int seg = (s & 7) ^ (row & 7);
    const u16* g = src + row * ld + seg * 8;
    u16* l = lds + (it * 256 + (tid & ~63)) * 8;  // wave-uniform base; HW adds lane*16
    GLOAD_LDS16(g, l);
  }
}

// ---------------- converts ----------------

__global__ __launch_bounds__(256) void cvt_x(const float* __restrict__ in,
                                             u16* __restrict__ out) {
  const int i = (int)blockIdx.x * 256 + (int)threadIdx.x;
  const float4 a = ((const float4*)in)[2 * i];
  const float4 b = ((const float4*)in)[2 * i + 1];
  u16x8 o;
  o[0] = f2bf(a.x); o[1] = f2bf(a.y); o[2] = f2bf(a.z); o[3] = f2bf(a.w);
  o[4] = f2bf(b.x); o[5] = f2bf(b.y); o[6] = f2bf(b.z); o[7] = f2bf(b.w);
  ((u16x8*)out)[i] = o;
}

// W [1024][1024] fp32 row-major -> Wt [1024][1024] bf16, Wt[n][k] = W[k][n]
// blockIdx.z selects which of the 4 weight matrices (merged launch)
__global__ __launch_bounds__(256) void cvt_w_t4(const float* __restrict__ W0,
                                                const float* __restrict__ W1,
                                                const float* __restrict__ W2,
                                                const float* __restrict__ W3,
                                                u16* __restrict__ T0, u16* __restrict__ T1,
                                                u16* __restrict__ T2, u16* __restrict__ T3) {
  const int z = (int)blockIdx.z;
  const float* W = z == 0 ? W0 : (z == 1 ? W1 : (z == 2 ? W2 : W3));
  u16* Wt = z == 0 ? T0 : (z == 1 ? T1 : (z == 2 ? T2 : T3));

  __shared__ u16 t[64][65];
  const int tid = (int)threadIdx.x;
  const int r = tid >> 2;
  const int cs = (tid & 3) * 16;
  const int tr = (int)blockIdx.y * 64;
  const int tc = (int)blockIdx.x * 64;
#pragma unroll
  for (int i = 0; i < 16; i += 4) {
    const float4 v = *(const float4*)&W[(size_t)(tr + r) * 1024 + tc + cs + i];
    t[r][cs + i + 0] = f2bf(v.x);
    t[r][cs + i + 1] = f2bf(v.y);
    t[r][cs + i + 2] = f2bf(v.z);
    t[r][cs + i + 3] = f2bf(v.w);
  }
  __syncthreads();
  u16 tmp[16];
#pragma unroll
  for (int i = 0; i < 16; ++i) tmp[i] = t[cs + i][r];
  u16x8 o0, o1;
#pragma unroll
  for (int i = 0; i < 8; ++i) { o0[i] = tmp[i]; o1[i] = tmp[8 + i]; }
  *(u16x8*)&Wt[(size_t)(tc + r) * 1024 + tr + cs] = o0;
  *(u16x8*)&Wt[(size_t)(tc + r) * 1024 + tr + cs + 8] = o1;
}

// ---------------- GEMM epilogue addressing helpers ----------------

__device__ __forceinline__ size_t vfrag_addr(int row, int col) {
  const int b = row >> 11, s = row & 2047;
  const int h = col >> 6, d = col & 63;
  return ((size_t)((b * 16 + h) * 32 + (s >> 6))) * 4096 + (size_t)(d >> 5) * 2048 +
         (size_t)((s & 63) >> 4) * 512 + (size_t)((d & 31) | (((s >> 3) & 1) << 5)) * 8 +
         (s & 7);
}

__device__ __forceinline__ size_t kfrag_addr(int row, int col) {
  const int b = row >> 11, s = row & 2047;
  const int h = col >> 6, d = col & 63;
  return ((size_t)((b * 16 + h) * 64 + (s >> 5))) * 2048 + (size_t)(d >> 4) * 512 +
         (size_t)((s & 31) | (((d >> 3) & 1) << 5)) * 8 + (d & 7);
}

// ---------------- GEMM K-loop core (128x128 tile, BK=64) ----------------
// Double-buffered LDS pipeline: stage tile t+1 BEFORE computing tile t;
// ONE barrier per K-step. LDS: buf b at lds + b*16384; A at +0, B at +8192.

__device__ __forceinline__ void compute_tile(const u16* __restrict__ buf, int wm, int wn,
                                             int lr, int lg, f32x4 (&acc)[4][4]) {
#pragma unroll
  for (int ks = 0; ks < 2; ++ks) {
    bf16x8 af[4], bf[4];
#pragma unroll
    for (int i = 0; i < 4; ++i) {
      const int ar = wm * 64 + i * 16 + lr;
      af[i] = load_frag(buf, ar * 128 + ((ks * 64 + lg * 16) ^ ((ar & 7) << 4)));
      const int br = wn * 64 + i * 16 + lr;
      bf[i] = load_frag(buf + 8192, br * 128 + ((ks * 64 + lg * 16) ^ ((br & 7) << 4)));
    }
#pragma unroll
    for (int mf = 0; mf < 4; ++mf)
#pragma unroll
      for (int nf = 0; nf < 4; ++nf) acc[mf][nf] = MFMA16(af[mf], bf[nf], acc[mf][nf]);
  }
}

__device__ __forceinline__ void gemm_core(const u16* __restrict__ Abase,
                                          const u16* __restrict__ Bbase, u16* lds, int tid,
                                          int wm, int wn, int lr, int lg,
                                          f32x4 (&acc)[4][4]) {
  constexpr int K = 1024;
  stage_tile<128>(Abase, K, lds, tid);
  stage_tile<128>(Bbase, K, lds + 8192, tid);
  __syncthreads();
  int cur = 0;
#pragma unroll 1
  for (int k0 = 64; k0 < K; k0 += 64) {
    u16* nbuf = lds + (cur ^ 1) * 16384;
    stage_tile<128>(Abase + k0, K, nbuf, tid);       // issue next-tile loads first
    stage_tile<128>(Bbase + k0, K, nbuf + 8192, tid);
    compute_tile(lds + cur * 16384, wm, wn, lr, lg, acc);  // MFMA hides load latency
    __syncthreads();
    cur ^= 1;
  }
  compute_tile(lds + cur * 16384, wm, wn, lr, lg, acc);
}

// ---------------- merged QKV GEMM: grid (24, 64) ----------------
// blockIdx.x>>3 selects matrix: 0=Q (row-major, scaled), 1=K (frag), 2=V (frag)

__global__ __launch_bounds__(256) void gemm_qkv(const u16* __restrict__ A,
                                                const u16* __restrict__ Bq,
                                                const u16* __restrict__ Bk,
                                                const u16* __restrict__ Bv,
                                                const float* __restrict__ bq,
                                                const float* __restrict__ bk,
                                                const float* __restrict__ bv,
                                                u16* __restrict__ Qo, u16* __restrict__ Ko,
                                                u16* __restrict__ Vo) {
  __shared__ __align__(16) u16 lds[32768];  // 64 KB: 2 dbuf x (A+B) x 128x64
  const int tid = (int)threadIdx.x;
  const int w = tid >> 6, lane = tid & 63;
  const int wm = w >> 1, wn = w & 1;
  const int lr = lane & 15, lg = lane >> 4;
  const int g = (int)blockIdx.x;
  const int m_idx = g >> 3, nt = g & 7;
  const int mt = (int)blockIdx.y;

  const u16* Bt = m_idx == 0 ? Bq : (m_idx == 1 ? Bk : Bv);
  const float* bias = m_idx == 0 ? bq : (m_idx == 1 ? bk : bv);

  f32x4 acc[4][4] = {};
  gemm_core(A + (size_t)mt * 128 * 1024, Bt + (size_t)nt * 128 * 1024, lds, tid, wm, wn, lr,
            lg, acc);

#pragma unroll
  for (int mf = 0; mf < 4; ++mf) {
#pragma unroll
    for (int nf = 0; nf < 4; ++nf) {
      const int col = nt * 128 + wn * 64 + nf * 16 + lr;
      const float bv2 = bias[col];
#pragma unroll
      for (int r = 0; r < 4; ++r) {
        const int row = mt * 128 + wm * 64 + mf * 16 + lg * 4 + r;
        const float v = acc[mf][nf][r] + bv2;
        if (m_idx == 0) {
          Qo[(size_t)row * 1024 + col] = f2bf(v * QSCALE);
        } else if (m_idx == 1) {
          Ko[kfrag_addr(row, col)] = f2bf(v);
        } else {
          Vo[vfrag_addr(row, col)] = f2bf(v);
        }
      }
    }
  }
}

// ---------------- final GEMM: out = Ab @ Wo^T + bo (fp32 out) ----------------

__global__ __launch_bounds__(256) void gemm_out(const u16* __restrict__ A,
                                                const u16* __restrict__ Bt,
                                                const float* __restrict__ bias,
                                                float* __restrict__ Cout) {
  __shared__ __align__(16) u16 lds[32768];
  const int tid = (int)threadIdx.x;
  const int w = tid >> 6, lane = tid & 63;
  const int wm = w >> 1, wn = w & 1;
  const int lr = lane & 15, lg = lane >> 4;
  const int mt = (int)blockIdx.y, nt = (int)blockIdx.x;

  f32x4 acc[4][4] = {};
  gemm_core(A + (size_t)mt * 128 * 1024, Bt + (size_t)nt * 128 * 1024, lds, tid, wm, wn, lr,
            lg, acc);

#pragma unroll
  for (int mf = 0; mf < 4; ++mf) {
#pragma unroll
    for (int nf = 0; nf < 4; ++nf) {
      const int col = nt * 128 + wn * 64 + nf * 16 + lr;
      const float bv = bias[col];
#pragma unroll
      for (int r = 0; r < 4; ++r) {
        const int row = mt * 128 + wm * 64 + mf * 16 + lg * 4 + r;
        Cout[(size_t)row * 1024 + col] = acc[mf][nf][r] + bv;
      }
    }
  }
}

// ---------------- flash attention (causal), swapped-operand, LDS-free ----------------
// 4-wave blocks; all 4 waves have IDENTICAL work (33 K/V tiles):
// wave w of block (xcd, rr, slot) does stripe qs0=slot*4+w of bh=(xcd<<3)|rr,
// then stripe 63-qs0 of bh^1 (same XCD L2 set). K ping-pong prefetch.
// NO min-occupancy launch_bounds: (256,4) capped VGPR at 64 -> spilled the
// f32x16 accumulators to scratch (r11: 2.5 GB HBM traffic, 557us). Let the
// allocator take ~120-136 VGPR; 3-4 blocks/CU is plenty.

__device__ __forceinline__ void loadK(bf16x8 (&kf)[2][4], const u16* __restrict__ p) {
#pragma unroll
  for (int sb = 0; sb < 2; ++sb)
#pragma unroll
    for (int dk = 0; dk < 4; ++dk)
      kf[sb][dk] = *(const bf16x8*)(p + sb * 2048 + dk * 512);
}

__device__ __forceinline__ void attn_tile(const bf16x8 (&kf)[2][4],
                                          const u16* __restrict__ vp_tile,
                                          const bf16x8 (&qf)[4], const int hi,
                                          const bool masked, const int tmask, f32x16& o0,
                                          f32x16& o1, float& m_run, float& l_run) {
  bf16x8 vf[2][4];
#pragma unroll
  for (int db = 0; db < 2; ++db)
#pragma unroll
    for (int ks = 0; ks < 4; ++ks)
      vf[db][ks] = *(const bf16x8*)(vp_tile + db * 2048 + ks * 512);

  // S^T: p0 = keys [0,32), p1 = keys [32,64); lane&31 = q, reg r -> k_local
  f32x16 p0 = {}, p1 = {};
#pragma unroll
  for (int dk = 0; dk < 4; ++dk) {
    p0 = MFMA32(kf[0][dk], qf[dk], p0);
    p1 = MFMA32(kf[1][dk], qf[dk], p1);
  }

  if (masked) {  // wave-uniform branch: only the last tile pays
#pragma unroll
    for (int r = 0; r < 16; ++r) {
      const int kl = (r & 3) + 8 * (r >> 2) + 4 * hi;
      if (kl > tmask) p0[r] = -1.0e30f;
      if (kl + 32 > tmask) p1[r] = -1.0e30f;
    }
  }

  // two parallel max chains (v_max3), then combine
  float mx0 = -3.0e38f, mx1 = -3.0e38f;
#pragma unroll
  for (int r = 0; r < 16; r += 2) {
    mx0 = fmaxf(mx0, fmaxf(p0[r], p0[r + 1]));
    mx1 = fmaxf(mx1, fmaxf(p1[r], p1[r + 1]));
  }
  float mx = fmaxf(mx0, mx1);
  mx = fmaxf(mx, __shfl_xor(mx, 32));

  // defer-max (T13): THR = 8 nats = 11.5416 log2-units
  if (__any(mx > m_run + 11.5416f)) {
    const float mnew = fmaxf(m_run, mx);
    const float alpha = EXP2(m_run - mnew);
    m_run = mnew;
    l_run *= alpha;
#pragma unroll
    for (int r = 0; r < 16; ++r) { o0[r] *= alpha; o1[r] *= alpha; }
  }

  // four parallel sum chains
  float rs0 = 0.f, rs1 = 0.f, rs2 = 0.f, rs3 = 0.f;
#pragma unroll
  for (int r = 0; r < 16; r += 2) {
    p0[r] = EXP2(p0[r] - m_run);
    p0[r + 1] = EXP2(p0[r + 1] - m_run);
    p1[r] = EXP2(p1[r] - m_run);
    p1[r + 1] = EXP2(p1[r + 1] - m_run);
    rs0 += p0[r];
    rs1 += p0[r + 1];
    rs2 += p1[r];
    rs3 += p1[r + 1];
  }
  float rs = (rs0 + rs1) + (rs2 + rs3);
  rs += __shfl_xor(rs, 32);
  l_run += rs;

  // P^T B-fragments: 16 cvt_pk words + 8 permlane32_swap
  unsigned c[16];
#pragma unroll
  for (int j = 0; j < 8; ++j) {
    c[j] = cvtpk(p0[2 * j], p0[2 * j + 1]);
    c[8 + j] = cvtpk(p1[2 * j], p1[2 * j + 1]);
  }
  bf16x8 pf[4];
#pragma unroll
  for (int ks = 0; ks < 4; ++ks) {
    const int base = (ks >> 1) * 8 + (ks & 1) * 4;
    auto s0 = __builtin_amdgcn_permlane32_swap(c[base + 0], c[base + 2], false, false);
    auto s1 = __builtin_amdgcn_permlane32_swap(c[base + 1], c[base + 3], false, false);
    u32x4 wv;
    wv[0] = s0[0];
    wv[1] = s1[0];
    wv[2] = s0[1];
    wv[3] = s1[1];
    pf[ks] = __builtin_bit_cast(bf16x8, wv);
  }

  // O^T += V^T . P^T
#pragma unroll
  for (int ks = 0; ks < 4; ++ks) {
    o0 = MFMA32(vf[0][ks], pf[ks], o0);
    o1 = MFMA32(vf[1][ks], pf[ks], o1);
  }
}

__global__ __launch_bounds__(256) void attn_fwd(const u16* __restrict__ Qb,
                                                const u16* __restrict__ Kf,
                                                const u16* __restrict__ Vf,
                                                u16* __restrict__ Ab) {
  const int tid = (int)threadIdx.x;
  const int w = tid >> 6, lane = tid & 63;
  const int ln = lane & 31, hi = lane >> 5;

  // grid 1024 = (xcd 8) x (bh-in-xcd 8) x (slot 16); 4 identical waves/block
  const int id = (int)blockIdx.x;
  const int xcd = id & 7;
  const int rr = (id >> 3) & 7;
  const int qs0 = (id >> 6) * 4 + w;  // 0..63

#pragma unroll 1
  for (int pass = 0; pass < 2; ++pass) {
    const int bh = (xcd << 3) | (pass ? (rr ^ 1) : rr);
    const int qs = pass ? 63 - qs0 : qs0;
    const int b = bh >> 4, h = bh & 15;
    const int wq = qs * 32;
    const int qrow = wq + ln;

    const u16* qp = Qb + (size_t)(b * 2048 + qrow) * 1024 + h * 64 + hi * 8;
    bf16x8 qf[4];
#pragma unroll
    for (int dk = 0; dk < 4; ++dk) qf[dk] = *(const bf16x8*)(qp + dk * 16);

    const u16* kp = Kf + (size_t)bh * 131072 + lane * 8;
    const u16* vp = Vf + (size_t)bh * 131072 + lane * 8;

    f32x16 o0 = {}, o1 = {};
    float m_run = -3.0e38f, l_run = 0.0f;

    const int nt = (qs >> 1) + 1;  // tiles incl. final masked one
    bf16x8 kA[2][4], kB[2][4];
    loadK(kA, kp);
    int i = 0;
    while (i + 2 <= nt) {
      loadK(kB, kp + (size_t)(i + 1) * 4096);
      attn_tile(kA, vp + (size_t)i * 4096, qf, hi, false, 0, o0, o1, m_run, l_run);
      const int nx = (i + 2 < nt) ? i + 2 : i + 1;
      loadK(kA, kp + (size_t)nx * 4096);
      attn_tile(kB, vp + (size_t)(i + 1) * 4096, qf, hi, i + 2 == nt, qrow - (i + 1) * 64,
                o0, o1, m_run, l_run);
      i += 2;
    }
    if (i < nt)
      attn_tile(kA, vp + (size_t)i * 4096, qf, hi, true, qrow - i * 64, o0, o1, m_run,
                l_run);

    const float inv = 1.0f / l_run;
    u16* op = Ab + (size_t)(b * 2048 + qrow) * 1024 + h * 64;
#pragma unroll
    for (int rr2 = 0; rr2 < 4; ++rr2) {
      u16x4 s0v, s1v;
#pragma unroll
      for (int cc = 0; cc < 4; ++cc) {
        s0v[cc] = f2bf(o0[rr2 * 4 + cc] * inv);
        s1v[cc] = f2bf(o1[rr2 * 4 + cc] * inv);
      }
      *(u16x4*)(op + rr2 * 8 + hi * 4) = s0v;       // d = 8*rr2 + 4*hi + 0..3
      *(u16x4*)(op + 32 + rr2 * 8 + hi * 4) = s1v;  // d = 32 + ...
    }
  }
}

// ---------------- launch ----------------

extern "C" void kernel_launch(void* const* d_in, const int* in_sizes, int n_in, void* d_out,
                              int out_size, void* d_ws, size_t ws_size, hipStream_t stream) {
  const float* X = (const float*)d_in[0];
  const float* Wq = (const float*)d_in[1];
  const float* bq = (const float*)d_in[2];
  const float* Wk = (const float*)d_in[3];
  const float* bk = (const float*)d_in[4];
  const float* Wv = (const float*)d_in[5];
  const float* bv = (const float*)d_in[6];
  const float* Wo = (const float*)d_in[7];
  const float* bo = (const float*)d_in[8];
  float* out = (float*)d_out;

  u16* ws = (u16*)d_ws;
  u16* Xb = ws;                    // 8192x1024 bf16 X
  u16* Wqt = Xb + 8388608;         // 1024x1024 bf16 Wq^T
  u16* Wkt = Wqt + 1048576;
  u16* Wvt = Wkt + 1048576;
  u16* Wot = Wvt + 1048576;
  u16* Qb = Wot + 1048576;         // 8192x1024 bf16 Q (pre-scaled by QSCALE)
  u16* Kf = Qb + 8388608;          // K fragment layout [bh][kb32][dk][lane][8]
  u16* Vf = Kf + 8388608;          // V fragment layout [bh][tile64][db][ks][lane][8]
  u16* Ab = Vf + 8388608;          // 8192x1024 bf16 attn out

  cvt_x<<<4096, 256, 0, stream>>>(X, Xb);
  dim3 wtg(16, 16, 4);
  cvt_w_t4<<<wtg, 256, 0, stream>>>(Wq, Wk, Wv, Wo, Wqt, Wkt, Wvt, Wot);

  dim3 qkvg(24, 64);
  gemm_qkv<<<qkvg, 256, 0, stream>>>(Xb, Wqt, Wkt, Wvt, bq, bk, bv, Qb, Kf, Vf);

  attn_fwd<<<1024, 256, 0, stream>>>(Qb, Kf, Vf, Ab);

  dim3 gg(8, 64);
  gemm_out<<<gg, 256, 0, stream>>>(Ab, Wot, bo, out);
}

// Round 13
// 164.790 us; speedup vs baseline: 3.8777x; 1.3979x over previous
//
#include <hip/hip_runtime.h>
#include <stdint.h>

typedef unsigned short u16;
typedef __bf16 bf16x2 __attribute__((ext_vector_type(2)));
typedef __bf16 bf16x8 __attribute__((ext_vector_type(8)));
typedef float f32x4 __attribute__((ext_vector_type(4)));
typedef float f32x16 __attribute__((ext_vector_type(16)));
typedef unsigned int u32x4 __attribute__((ext_vector_type(4)));
typedef u16 u16x8 __attribute__((ext_vector_type(8)));
typedef u16 u16x4 __attribute__((ext_vector_type(4)));

#define MFMA16(a, b, c) __builtin_amdgcn_mfma_f32_16x16x32_bf16((a), (b), (c), 0, 0, 0)
#define MFMA32(a, b, c) __builtin_amdgcn_mfma_f32_32x32x16_bf16((a), (b), (c), 0, 0, 0)

// 0.125 (1/sqrt(64)) * log2(e): folded into Q so softmax uses exp2 directly
#define QSCALE 0.18033688011112042f

#if defined(__has_builtin)
#if __has_builtin(__builtin_amdgcn_exp2f)
#define EXP2(x) __builtin_amdgcn_exp2f(x)
#endif
#endif
#ifndef EXP2
#define EXP2(x) __expf((x) * 0.6931471805599453f)
#endif

__device__ __forceinline__ u16 f2bf(float f) {
  return __builtin_bit_cast(u16, (__bf16)f);  // RNE
}

__device__ __forceinline__ unsigned cvtpk(float lo, float hi) {
  bf16x2 t;
  t[0] = (__bf16)lo;
  t[1] = (__bf16)hi;
  return __builtin_bit_cast(unsigned, t);  // v_cvt_pk_bf16_f32
}

__device__ __forceinline__ bf16x8 load_frag(const u16* lds_base, int byteoff) {
  u32x4 v = *(const u32x4*)((const char*)lds_base + byteoff);
  return __builtin_bit_cast(bf16x8, v);
}

#define GLOAD_LDS16(gp, lp)                                                        \
  __builtin_amdgcn_global_load_lds((const __attribute__((address_space(1))) void*)(gp), \
                                   (__attribute__((address_space(3))) void*)(lp), 16, 0, 0)

// Stage ROWS x 64-bf16 tile (128B rows) from global (row stride ld elems) into
// swizzled LDS. Physical 16B-slot `seg` holds logical slot `seg ^ (row&7)`.
template <int ROWS>
__device__ __forceinline__ void stage_tile(const u16* __restrict__ src, int ld, u16* lds,
                                           int tid) {
  constexpr int SLOTS = ROWS * 8;
#pragma unroll
  for (int it = 0; it < SLOTS / 256; ++it) {
    const int s = it * 256 + tid;
    const int row = s >> 3;
    const int seg = (s & 7) ^ (row & 7);
    const u16* g = src + row * ld + seg * 8;
    u16* l = lds + (it * 256 + (tid & ~63)) * 8;  // wave-uniform base; HW adds lane*16
    GLOAD_LDS16(g, l);
  }
}

// ---------------- converts ----------------

__global__ __launch_bounds__(256) void cvt_x(const float* __restrict__ in,
                                             u16* __restrict__ out) {
  const int i = (int)blockIdx.x * 256 + (int)threadIdx.x;
  const float4 a = ((const float4*)in)[2 * i];
  const float4 b = ((const float4*)in)[2 * i + 1];
  u16x8 o;
  o[0] = f2bf(a.x); o[1] = f2bf(a.y); o[2] = f2bf(a.z); o[3] = f2bf(a.w);
  o[4] = f2bf(b.x); o[5] = f2bf(b.y); o[6] = f2bf(b.z); o[7] = f2bf(b.w);
  ((u16x8*)out)[i] = o;
}

// W [1024][1024] fp32 row-major -> Wt [1024][1024] bf16, Wt[n][k] = W[k][n]
// blockIdx.z selects which of the 4 weight matrices (merged launch)
__global__ __launch_bounds__(256) void cvt_w_t4(const float* __restrict__ W0,
                                                const float* __restrict__ W1,
                                                const float* __restrict__ W2,
                                                const float* __restrict__ W3,
                                                u16* __restrict__ T0, u16* __restrict__ T1,
                                                u16* __restrict__ T2, u16* __restrict__ T3) {
  const int z = (int)blockIdx.z;
  const float* W = z == 0 ? W0 : (z == 1 ? W1 : (z == 2 ? W2 : W3));
  u16* Wt = z == 0 ? T0 : (z == 1 ? T1 : (z == 2 ? T2 : T3));

  __shared__ u16 t[64][65];
  const int tid = (int)threadIdx.x;
  const int r = tid >> 2;
  const int cs = (tid & 3) * 16;
  const int tr = (int)blockIdx.y * 64;
  const int tc = (int)blockIdx.x * 64;
#pragma unroll
  for (int i = 0; i < 16; i += 4) {
    const float4 v = *(const float4*)&W[(size_t)(tr + r) * 1024 + tc + cs + i];
    t[r][cs + i + 0] = f2bf(v.x);
    t[r][cs + i + 1] = f2bf(v.y);
    t[r][cs + i + 2] = f2bf(v.z);
    t[r][cs + i + 3] = f2bf(v.w);
  }
  __syncthreads();
  u16 tmp[16];
#pragma unroll
  for (int i = 0; i < 16; ++i) tmp[i] = t[cs + i][r];
  u16x8 o0, o1;
#pragma unroll
  for (int i = 0; i < 8; ++i) { o0[i] = tmp[i]; o1[i] = tmp[8 + i]; }
  *(u16x8*)&Wt[(size_t)(tc + r) * 1024 + tr + cs] = o0;
  *(u16x8*)&Wt[(size_t)(tc + r) * 1024 + tr + cs + 8] = o1;
}

// ---------------- GEMM epilogue addressing helpers ----------------

__device__ __forceinline__ size_t vfrag_addr(int row, int col) {
  const int b = row >> 11, s = row & 2047;
  const int h = col >> 6, d = col & 63;
  return ((size_t)((b * 16 + h) * 32 + (s >> 6))) * 4096 + (size_t)(d >> 5) * 2048 +
         (size_t)((s & 63) >> 4) * 512 + (size_t)((d & 31) | (((s >> 3) & 1) << 5)) * 8 +
         (s & 7);
}

__device__ __forceinline__ size_t kfrag_addr(int row, int col) {
  const int b = row >> 11, s = row & 2047;
  const int h = col >> 6, d = col & 63;
  return ((size_t)((b * 16 + h) * 64 + (s >> 5))) * 2048 + (size_t)(d >> 4) * 512 +
         (size_t)((s & 31) | (((d >> 3) & 1) << 5)) * 8 + (d & 7);
}

// ---------------- GEMM K-loop core (128x128 tile, BK=64) ----------------
// Double-buffered LDS pipeline: stage tile t+1 BEFORE computing tile t;
// ONE barrier per K-step. LDS: buf b at lds + b*16384; A at +0, B at +8192.

__device__ __forceinline__ void compute_tile(const u16* __restrict__ buf, int wm, int wn,
                                             int lr, int lg, f32x4 (&acc)[4][4]) {
#pragma unroll
  for (int ks = 0; ks < 2; ++ks) {
    bf16x8 af[4], bf[4];
#pragma unroll
    for (int i = 0; i < 4; ++i) {
      const int ar = wm * 64 + i * 16 + lr;
      af[i] = load_frag(buf, ar * 128 + ((ks * 64 + lg * 16) ^ ((ar & 7) << 4)));
      const int br = wn * 64 + i * 16 + lr;
      bf[i] = load_frag(buf + 8192, br * 128 + ((ks * 64 + lg * 16) ^ ((br & 7) << 4)));
    }
#pragma unroll
    for (int mf = 0; mf < 4; ++mf)
#pragma unroll
      for (int nf = 0; nf < 4; ++nf) acc[mf][nf] = MFMA16(af[mf], bf[nf], acc[mf][nf]);
  }
}

__device__ __forceinline__ void gemm_core(const u16* __restrict__ Abase,
                                          const u16* __restrict__ Bbase, u16* lds, int tid,
                                          int wm, int wn, int lr, int lg,
                                          f32x4 (&acc)[4][4]) {
  constexpr int K = 1024;
  stage_tile<128>(Abase, K, lds, tid);
  stage_tile<128>(Bbase, K, lds + 8192, tid);
  __syncthreads();
  int cur = 0;
#pragma unroll 1
  for (int k0 = 64; k0 < K; k0 += 64) {
    u16* nbuf = lds + (cur ^ 1) * 16384;
    stage_tile<128>(Abase + k0, K, nbuf, tid);       // issue next-tile loads first
    stage_tile<128>(Bbase + k0, K, nbuf + 8192, tid);
    compute_tile(lds + cur * 16384, wm, wn, lr, lg, acc);  // MFMA hides load latency
    __syncthreads();
    cur ^= 1;
  }
  compute_tile(lds + cur * 16384, wm, wn, lr, lg, acc);
}

// ---------------- merged QKV GEMM: grid (24, 64) ----------------
// blockIdx.x>>3 selects matrix: 0=Q (row-major, scaled), 1=K (frag), 2=V (frag)

__global__ __launch_bounds__(256) void gemm_qkv(const u16* __restrict__ A,
                                                const u16* __restrict__ Bq,
                                                const u16* __restrict__ Bk,
                                                const u16* __restrict__ Bv,
                                                const float* __restrict__ bq,
                                                const float* __restrict__ bk,
                                                const float* __restrict__ bv,
                                                u16* __restrict__ Qo, u16* __restrict__ Ko,
                                                u16* __restrict__ Vo) {
  __shared__ __align__(16) u16 lds[32768];  // 64 KB: 2 dbuf x (A+B) x 128x64
  const int tid = (int)threadIdx.x;
  const int w = tid >> 6, lane = tid & 63;
  const int wm = w >> 1, wn = w & 1;
  const int lr = lane & 15, lg = lane >> 4;
  const int g = (int)blockIdx.x;
  const int m_idx = g >> 3, nt = g & 7;
  const int mt = (int)blockIdx.y;

  const u16* Bt = m_idx == 0 ? Bq : (m_idx == 1 ? Bk : Bv);
  const float* bias = m_idx == 0 ? bq : (m_idx == 1 ? bk : bv);

  f32x4 acc[4][4] = {};
  gemm_core(A + (size_t)mt * 128 * 1024, Bt + (size_t)nt * 128 * 1024, lds, tid, wm, wn, lr,
            lg, acc);

#pragma unroll
  for (int mf = 0; mf < 4; ++mf) {
#pragma unroll
    for (int nf = 0; nf < 4; ++nf) {
      const int col = nt * 128 + wn * 64 + nf * 16 + lr;
      const float bv2 = bias[col];
#pragma unroll
      for (int r = 0; r < 4; ++r) {
        const int row = mt * 128 + wm * 64 + mf * 16 + lg * 4 + r;
        const float v = acc[mf][nf][r] + bv2;
        if (m_idx == 0) {
          Qo[(size_t)row * 1024 + col] = f2bf(v * QSCALE);
        } else if (m_idx == 1) {
          Ko[kfrag_addr(row, col)] = f2bf(v);
        } else {
          Vo[vfrag_addr(row, col)] = f2bf(v);
        }
      }
    }
  }
}

// ---------------- final GEMM: out = Ab @ Wo^T + bo (fp32 out) ----------------

__global__ __launch_bounds__(256) void gemm_out(const u16* __restrict__ A,
                                                const u16* __restrict__ Bt,
                                                const float* __restrict__ bias,
                                                float* __restrict__ Cout) {
  __shared__ __align__(16) u16 lds[32768];
  const int tid = (int)threadIdx.x;
  const int w = tid >> 6, lane = tid & 63;
  const int wm = w >> 1, wn = w & 1;
  const int lr = lane & 15, lg = lane >> 4;
  const int mt = (int)blockIdx.y, nt = (int)blockIdx.x;

  f32x4 acc[4][4] = {};
  gemm_core(A + (size_t)mt * 128 * 1024, Bt + (size_t)nt * 128 * 1024, lds, tid, wm, wn, lr,
            lg, acc);

#pragma unroll
  for (int mf = 0; mf < 4; ++mf) {
#pragma unroll
    for (int nf = 0; nf < 4; ++nf) {
      const int col = nt * 128 + wn * 64 + nf * 16 + lr;
      const float bv = bias[col];
#pragma unroll
      for (int r = 0; r < 4; ++r) {
        const int row = mt * 128 + wm * 64 + mf * 16 + lg * 4 + r;
        Cout[(size_t)row * 1024 + col] = acc[mf][nf][r] + bv;
      }
    }
  }
}

// ---------------- flash attention (causal), swapped-operand, LDS-free ----------------
// REVERTED to the empirically best variant (r6, 66us): 1-wave blocks, grid 4096,
// heavy-first dispatch, K ping-pong prefetch, SIMPLE reduction chains.
// (r10's "split chains" caused scratch spills: WRITE_SIZE 16->33MB, VALU-busy
// 35->76us. Keep live ranges short: consume p values in order.)

__device__ __forceinline__ void loadK(bf16x8 (&kf)[2][4], const u16* __restrict__ p) {
#pragma unroll
  for (int sb = 0; sb < 2; ++sb)
#pragma unroll
    for (int dk = 0; dk < 4; ++dk)
      kf[sb][dk] = *(const bf16x8*)(p + sb * 2048 + dk * 512);
}

__device__ __forceinline__ void attn_tile(const bf16x8 (&kf)[2][4],
                                          const u16* __restrict__ vp_tile,
                                          const bf16x8 (&qf)[4], const int hi,
                                          const bool masked, const int tmask, f32x16& o0,
                                          f32x16& o1, float& m_run, float& l_run) {
  bf16x8 vf[2][4];
#pragma unroll
  for (int db = 0; db < 2; ++db)
#pragma unroll
    for (int ks = 0; ks < 4; ++ks)
      vf[db][ks] = *(const bf16x8*)(vp_tile + db * 2048 + ks * 512);

  // S^T: p0 = keys [0,32), p1 = keys [32,64); lane&31 = q, reg r -> k_local
  f32x16 p0 = {}, p1 = {};
#pragma unroll
  for (int dk = 0; dk < 4; ++dk) {
    p0 = MFMA32(kf[0][dk], qf[dk], p0);
    p1 = MFMA32(kf[1][dk], qf[dk], p1);
  }

  if (masked) {  // wave-uniform branch: only the last tile pays
#pragma unroll
    for (int r = 0; r < 16; ++r) {
      const int kl = (r & 3) + 8 * (r >> 2) + 4 * hi;
      if (kl > tmask) p0[r] = -1.0e30f;
      if (kl + 32 > tmask) p1[r] = -1.0e30f;
    }
  }

  float mx = -3.0e38f;
#pragma unroll
  for (int r = 0; r < 16; ++r) mx = fmaxf(mx, fmaxf(p0[r], p1[r]));  // v_max3
  mx = fmaxf(mx, __shfl_xor(mx, 32));

  // defer-max (T13): THR = 8 nats = 11.5416 log2-units
  if (__any(mx > m_run + 11.5416f)) {
    const float mnew = fmaxf(m_run, mx);
    const float alpha = EXP2(m_run - mnew);
    m_run = mnew;
    l_run *= alpha;
#pragma unroll
    for (int r = 0; r < 16; ++r) { o0[r] *= alpha; o1[r] *= alpha; }
  }

  float rs = 0.0f;
#pragma unroll
  for (int r = 0; r < 16; ++r) {
    p0[r] = EXP2(p0[r] - m_run);
    p1[r] = EXP2(p1[r] - m_run);
    rs += p0[r] + p1[r];
  }
  rs += __shfl_xor(rs, 32);
  l_run += rs;

  // P^T B-fragments: 16 cvt_pk words + 8 permlane32_swap
  unsigned c[16];
#pragma unroll
  for (int j = 0; j < 8; ++j) {
    c[j] = cvtpk(p0[2 * j], p0[2 * j + 1]);
    c[8 + j] = cvtpk(p1[2 * j], p1[2 * j + 1]);
  }
  bf16x8 pf[4];
#pragma unroll
  for (int ks = 0; ks < 4; ++ks) {
    const int base = (ks >> 1) * 8 + (ks & 1) * 4;
    auto s0 = __builtin_amdgcn_permlane32_swap(c[base + 0], c[base + 2], false, false);
    auto s1 = __builtin_amdgcn_permlane32_swap(c[base + 1], c[base + 3], false, false);
    u32x4 wv;
    wv[0] = s0[0];
    wv[1] = s1[0];
    wv[2] = s0[1];
    wv[3] = s1[1];
    pf[ks] = __builtin_bit_cast(bf16x8, wv);
  }

  // O^T += V^T . P^T
#pragma unroll
  for (int ks = 0; ks < 4; ++ks) {
    o0 = MFMA32(vf[0][ks], pf[ks], o0);
    o1 = MFMA32(vf[1][ks], pf[ks], o1);
  }
}

__global__ __launch_bounds__(64) void attn_fwd(const u16* __restrict__ Qb,
                                               const u16* __restrict__ Kf,
                                               const u16* __restrict__ Vf,
                                               u16* __restrict__ Ab) {
  const int lane = (int)threadIdx.x;
  const int ln = lane & 31, hi = lane >> 5;

  // 1-wave blocks: xcd co-location for K/V L2 locality + heavy-first order;
  // balance comes from dynamic oversubscription (16 blocks/CU nominal).
  const int id = (int)blockIdx.x;
  const int xcd = id & 7, r = id >> 3;
  const int bh = (xcd << 3) | (r & 7);
  const int qs = 63 - (r >> 3);  // 32-row q-stripe, heavy first
  const int b = bh >> 4, h = bh & 15;
  const int wq = qs * 32;
  const int qrow = wq + ln;

  const u16* qp = Qb + (size_t)(b * 2048 + qrow) * 1024 + h * 64 + hi * 8;
  bf16x8 qf[4];
#pragma unroll
  for (int dk = 0; dk < 4; ++dk) qf[dk] = *(const bf16x8*)(qp + dk * 16);

  // fragment-layout bases (per-lane contiguous 16B)
  const u16* kp = Kf + (size_t)bh * 131072 + lane * 8;
  const u16* vp = Vf + (size_t)bh * 131072 + lane * 8;

  f32x16 o0 = {}, o1 = {};
  float m_run = -3.0e38f, l_run = 0.0f;

  const int nt = (qs >> 1) + 1;  // tiles incl. final masked one
  bf16x8 kA[2][4], kB[2][4];
  loadK(kA, kp);
  int i = 0;
  while (i + 2 <= nt) {
    loadK(kB, kp + (size_t)(i + 1) * 4096);
    attn_tile(kA, vp + (size_t)i * 4096, qf, hi, false, 0, o0, o1, m_run, l_run);
    const int nx = (i + 2 < nt) ? i + 2 : i + 1;
    loadK(kA, kp + (size_t)nx * 4096);
    attn_tile(kB, vp + (size_t)(i + 1) * 4096, qf, hi, i + 2 == nt, qrow - (i + 1) * 64,
              o0, o1, m_run, l_run);
    i += 2;
  }
  if (i < nt)
    attn_tile(kA, vp + (size_t)i * 4096, qf, hi, true, qrow - i * 64, o0, o1, m_run, l_run);

  const float inv = 1.0f / l_run;
  u16* op = Ab + (size_t)(b * 2048 + qrow) * 1024 + h * 64;
#pragma unroll
  for (int rr = 0; rr < 4; ++rr) {
    u16x4 s0v, s1v;
#pragma unroll
    for (int cc = 0; cc < 4; ++cc) {
      s0v[cc] = f2bf(o0[rr * 4 + cc] * inv);
      s1v[cc] = f2bf(o1[rr * 4 + cc] * inv);
    }
    *(u16x4*)(op + rr * 8 + hi * 4) = s0v;       // d = 8*rr + 4*hi + 0..3
    *(u16x4*)(op + 32 + rr * 8 + hi * 4) = s1v;  // d = 32 + ...
  }
}

// ---------------- launch ----------------

extern "C" void kernel_launch(void* const* d_in, const int* in_sizes, int n_in, void* d_out,
                              int out_size, void* d_ws, size_t ws_size, hipStream_t stream) {
  const float* X = (const float*)d_in[0];
  const float* Wq = (const float*)d_in[1];
  const float* bq = (const float*)d_in[2];
  const float* Wk = (const float*)d_in[3];
  const float* bk = (const float*)d_in[4];
  const float* Wv = (const float*)d_in[5];
  const float* bv = (const float*)d_in[6];
  const float* Wo = (const float*)d_in[7];
  const float* bo = (const float*)d_in[8];
  float* out = (float*)d_out;

  u16* ws = (u16*)d_ws;
  u16* Xb = ws;                    // 8192x1024 bf16 X
  u16* Wqt = Xb + 8388608;         // 1024x1024 bf16 Wq^T
  u16* Wkt = Wqt + 1048576;
  u16* Wvt = Wkt + 1048576;
  u16* Wot = Wvt + 1048576;
  u16* Qb = Wot + 1048576;         // 8192x1024 bf16 Q (pre-scaled by QSCALE)
  u16* Kf = Qb + 8388608;          // K fragment layout [bh][kb32][dk][lane][8]
  u16* Vf = Kf + 8388608;          // V fragment layout [bh][tile64][db][ks][lane][8]
  u16* Ab = Vf + 8388608;          // 8192x1024 bf16 attn out

  cvt_x<<<4096, 256, 0, stream>>>(X, Xb);
  dim3 wtg(16, 16, 4);
  cvt_w_t4<<<wtg, 256, 0, stream>>>(Wq, Wk, Wv, Wo, Wqt, Wkt, Wvt, Wot);

  dim3 qkvg(24, 64);
  gemm_qkv<<<qkvg, 256, 0, stream>>>(Xb, Wqt, Wkt, Wvt, bq, bk, bv, Qb, Kf, Vf);

  attn_fwd<<<4096, 64, 0, stream>>>(Qb, Kf, Vf, Ab);

  dim3 gg(8, 64);
  gemm_out<<<gg, 256, 0, stream>>>(Ab, Wot, bo, out);
}